// Round 1
// baseline (834.182 us; speedup 1.0000x reference)
//
#include <hip/hip_runtime.h>

constexpr int FEAT = 128;

// ---------------- CSR build ----------------

__global__ void count_kernel(const int* __restrict__ dst, int* __restrict__ deg, int E) {
  int e = blockIdx.x * blockDim.x + threadIdx.x;
  if (e < E) atomicAdd(&deg[dst[e]], 1);
}

__global__ __launch_bounds__(1024) void scan_kernel(const int* __restrict__ in,
                                                    int* __restrict__ out, int n) {
  // single-block exclusive scan, 1024 threads, chunked
  __shared__ int wsum[16];
  __shared__ int carry;
  int tid = threadIdx.x;
  if (tid == 0) carry = 0;
  __syncthreads();
  int lane = tid & 63, wid = tid >> 6;
  for (int base = 0; base < n; base += 1024) {
    int i = base + tid;
    int v = (i < n) ? in[i] : 0;
    int s = v;
#pragma unroll
    for (int off = 1; off < 64; off <<= 1) {
      int t = __shfl_up(s, off);
      if (lane >= off) s += t;
    }
    if (lane == 63) wsum[wid] = s;
    __syncthreads();
    if (tid < 16) {
      int ws2 = wsum[tid];
#pragma unroll
      for (int off = 1; off < 16; off <<= 1) {
        int t = __shfl_up(ws2, off, 16);
        if ((tid & 15) >= off) ws2 += t;
      }
      wsum[tid] = ws2;
    }
    __syncthreads();
    int excl = carry + (wid ? wsum[wid - 1] : 0) + (s - v);
    if (i < n) out[i] = excl;
    __syncthreads();
    if (tid == 0) carry += wsum[15];
    __syncthreads();
  }
}

__global__ void fill_kernel(const int* __restrict__ src, const int* __restrict__ dst,
                            int* __restrict__ cursor, int* __restrict__ col, int E) {
  int e = blockIdx.x * blockDim.x + threadIdx.x;
  if (e < E) {
    int p = atomicAdd(&cursor[dst[e]], 1);
    col[p] = src[e];
  }
}

// ---------------- aggregation: one wave per node, float2 per lane ----------------

__global__ void agg_kernel(const float* __restrict__ x, const int* __restrict__ rowptr,
                           const int* __restrict__ col, float* __restrict__ agg, int N) {
  int gid = blockIdx.x * blockDim.x + threadIdx.x;
  int node = gid >> 6;
  if (node >= N) return;
  int lane = threadIdx.x & 63;
  float2 acc = ((const float2*)(x + (size_t)node * FEAT))[lane];
  int e0 = rowptr[node], e1 = rowptr[node + 1];
  for (int e = e0; e < e1; e++) {
    float2 v = ((const float2*)(x + (size_t)col[e] * FEAT))[lane];
    acc.x += v.x;
    acc.y += v.y;
  }
  ((float2*)(agg + (size_t)node * FEAT))[lane] = acc;
}

// ---------------- fp32 GEMM: C = relu(A[ N x128 ] @ W[128x128] + b), optional col stats ----------------
// 128x128 tile, 256 threads, 8x8 per-thread, A transposed in LDS (stride 129), K chunked by 64.

__global__ __launch_bounds__(256) void gemm_kernel(
    const float* __restrict__ A, const float* __restrict__ W,
    const float* __restrict__ bias, float* __restrict__ C,
    float* __restrict__ colsum, float* __restrict__ colsumsq,
    int N, int doStats) {
  __shared__ float At[64 * 129];   // [k][row], padded
  __shared__ float Ws[64 * 128];   // [k][c]
  __shared__ float ls[128], lq[128];
  int tx = threadIdx.x;
  int row0 = blockIdx.x * 128;
  if (tx < 128) { ls[tx] = 0.f; lq[tx] = 0.f; }

  int rg = (tx >> 4) << 3;  // row offset 0..120
  int cb = tx & 15;         // col base; cols = cb + 16*j
  float acc[8][8];
#pragma unroll
  for (int i = 0; i < 8; i++)
#pragma unroll
    for (int j = 0; j < 8; j++) acc[i][j] = 0.f;

  for (int kc = 0; kc < 128; kc += 64) {
    __syncthreads();
#pragma unroll
    for (int i = 0; i < 8; i++) {
      int idx = tx + i * 256;  // 2048 float4 = 64x128
      ((float4*)Ws)[idx] = ((const float4*)(W + kc * 128))[idx];
    }
#pragma unroll
    for (int i = 0; i < 8; i++) {
      int idx = tx + i * 256;  // 2048 float4 = 128 rows x 16
      int r = idx >> 4;
      int k4 = (idx & 15) << 2;
      float4 v = make_float4(0.f, 0.f, 0.f, 0.f);
      if (row0 + r < N)
        v = ((const float4*)(A + (size_t)(row0 + r) * FEAT + kc))[idx & 15];
      At[(k4 + 0) * 129 + r] = v.x;
      At[(k4 + 1) * 129 + r] = v.y;
      At[(k4 + 2) * 129 + r] = v.z;
      At[(k4 + 3) * 129 + r] = v.w;
    }
    __syncthreads();
#pragma unroll 4
    for (int kk = 0; kk < 64; kk++) {
      float a[8], w[8];
#pragma unroll
      for (int i = 0; i < 8; i++) a[i] = At[kk * 129 + rg + i];
#pragma unroll
      for (int j = 0; j < 8; j++) w[j] = Ws[kk * 128 + cb + 16 * j];
#pragma unroll
      for (int i = 0; i < 8; i++)
#pragma unroll
        for (int j = 0; j < 8; j++) acc[i][j] = fmaf(a[i], w[j], acc[i][j]);
    }
  }

  float bj[8];
#pragma unroll
  for (int j = 0; j < 8; j++) bj[j] = bias[cb + 16 * j];
  float psum[8], psq[8];
#pragma unroll
  for (int j = 0; j < 8; j++) { psum[j] = 0.f; psq[j] = 0.f; }
#pragma unroll
  for (int i = 0; i < 8; i++) {
    int r = row0 + rg + i;
    if (r < N) {
#pragma unroll
      for (int j = 0; j < 8; j++) {
        float v = acc[i][j] + bj[j];
        v = v > 0.f ? v : 0.f;
        C[(size_t)r * FEAT + cb + 16 * j] = v;
        psum[j] += v;
        psq[j] += v * v;
      }
    }
  }
  if (doStats) {
#pragma unroll
    for (int j = 0; j < 8; j++) {
      atomicAdd(&ls[cb + 16 * j], psum[j]);
      atomicAdd(&lq[cb + 16 * j], psq[j]);
    }
    __syncthreads();
    if (tx < 128) {
      atomicAdd(&colsum[tx], ls[tx]);
      atomicAdd(&colsumsq[tx], lq[tx]);
    }
  }
}

// ---------------- fold BN affine into second-GEMM weights ----------------

__global__ __launch_bounds__(128) void fold_kernel(
    const float* __restrict__ colsum, const float* __restrict__ colsumsq,
    const float* __restrict__ gamma, const float* __restrict__ beta,
    const float* __restrict__ w2, const float* __restrict__ b2,
    float* __restrict__ w2f, float* __restrict__ b2f, int N) {
  __shared__ float sc[128], sh[128];
  int c = threadIdx.x;
  float invN = 1.0f / (float)N;
  float mean = colsum[c] * invN;
  float var = colsumsq[c] * invN - mean * mean;
  float rstd = rsqrtf(var + 1e-5f);
  float scale = gamma[c] * rstd;
  float shift = beta[c] - mean * scale;
  sc[c] = scale;
  sh[c] = shift;
  __syncthreads();
  float bacc = b2[c];
  for (int k = 0; k < 128; k++) {
    float wv = w2[k * 128 + c];
    w2f[k * 128 + c] = sc[k] * wv;
    bacc += sh[k] * wv;
  }
  b2f[c] = bacc;
}

// ---------------- final fc2: out[i] = dot(h[i], w) + b ----------------

__global__ void fc2_kernel(const float* __restrict__ h, const float* __restrict__ w,
                           const float* __restrict__ b, float* __restrict__ out, int N) {
  int gid = blockIdx.x * blockDim.x + threadIdx.x;
  int node = gid >> 6;
  if (node >= N) return;
  int lane = threadIdx.x & 63;
  float2 hv = ((const float2*)(h + (size_t)node * FEAT))[lane];
  float2 wv = ((const float2*)w)[lane];
  float s = hv.x * wv.x + hv.y * wv.y;
#pragma unroll
  for (int off = 32; off; off >>= 1) s += __shfl_xor(s, off);
  if (lane == 0) out[node] = s + b[0];
}

// ---------------- launch ----------------

extern "C" void kernel_launch(void* const* d_in, const int* in_sizes, int n_in,
                              void* d_out, int out_size, void* d_ws, size_t ws_size,
                              hipStream_t stream) {
  const float* x     = (const float*)d_in[0];
  const int*   ei    = (const int*)d_in[1];
  const float* w1    = (const float*)d_in[2];
  const float* b1    = (const float*)d_in[3];
  const float* gamma = (const float*)d_in[4];
  const float* beta  = (const float*)d_in[5];
  const float* w2    = (const float*)d_in[6];
  const float* b2    = (const float*)d_in[7];
  const float* fc1w  = (const float*)d_in[8];
  const float* fc1b  = (const float*)d_in[9];
  const float* fc2w  = (const float*)d_in[10];
  const float* fc2b  = (const float*)d_in[11];
  float* out = (float*)d_out;

  int N = in_sizes[0] / FEAT;  // 50000
  int E = in_sizes[1] / 2;     // 600000
  const int* srcI = ei;
  const int* dstI = ei + E;

  float* ws_f = (float*)d_ws;
  size_t bigoff = (size_t)N * FEAT;
  float* fA = ws_f;
  float* fB = ws_f + bigoff;
  float* w2f = ws_f + 2 * bigoff;
  float* b2f = w2f + FEAT * FEAT;
  float* colsum = b2f + FEAT;
  float* colsumsq = colsum + FEAT;
  int* deg = (int*)(colsumsq + FEAT);
  int* rowptr = deg + (N + 1);
  int* cursor = rowptr + (N + 1);
  int* col = cursor + (N + 1);

  // CSR build (per call; inputs are restored before every timed call)
  hipMemsetAsync(deg, 0, (N + 1) * sizeof(int), stream);
  count_kernel<<<(E + 255) / 256, 256, 0, stream>>>(dstI, deg, E);
  scan_kernel<<<1, 1024, 0, stream>>>(deg, rowptr, N + 1);
  hipMemcpyAsync(cursor, rowptr, (N + 1) * sizeof(int), hipMemcpyDeviceToDevice, stream);
  fill_kernel<<<(E + 255) / 256, 256, 0, stream>>>(srcI, dstI, cursor, col, E);

  int aggBlocks = (N * 64 + 255) / 256;
  int gemmBlocks = (N + 127) / 128;

  const float* hin = x;
  float* bufs[2] = {fA, fB};
  int cur = 0;
  for (int l = 0; l < 4; l++) {
    float* aggb = bufs[cur];      // agg target, later overwritten with layer output
    float* h1b = bufs[cur ^ 1];   // hidden after gemm1
    agg_kernel<<<aggBlocks, 256, 0, stream>>>(hin, rowptr, col, aggb, N);
    hipMemsetAsync(colsum, 0, 2 * FEAT * sizeof(float), stream);
    gemm_kernel<<<gemmBlocks, 256, 0, stream>>>(aggb, w1 + (size_t)l * FEAT * FEAT,
                                                b1 + (size_t)l * FEAT, h1b, colsum,
                                                colsumsq, N, 1);
    fold_kernel<<<1, FEAT, 0, stream>>>(colsum, colsumsq, gamma + (size_t)l * FEAT,
                                        beta + (size_t)l * FEAT,
                                        w2 + (size_t)l * FEAT * FEAT,
                                        b2 + (size_t)l * FEAT, w2f, b2f, N);
    gemm_kernel<<<gemmBlocks, 256, 0, stream>>>(h1b, w2f, b2f, aggb, colsum, colsumsq, N, 0);
    hin = aggb;
    cur ^= 1;
  }

  float* fcbuf = (hin == fA) ? fB : fA;
  gemm_kernel<<<gemmBlocks, 256, 0, stream>>>(hin, fc1w, fc1b, fcbuf, colsum, colsumsq, N, 0);
  fc2_kernel<<<aggBlocks, 256, 0, stream>>>(fcbuf, fc2w, fc2b, out, N);
}